// Round 1
// baseline (502.341 us; speedup 1.0000x reference)
//
#include <hip/hip_runtime.h>

#define BLOCK 256
#define GRID 2048
#define NWAVES (BLOCK / 64)

// per-element BCE-with-logits: max(x,0) - x*t + log(1 + exp(-|x|))
// == softplus(x) for t=0, softplus(-x) for t=1  (matches -where(t==0, -sp(x), -sp(-x)))
__device__ __forceinline__ float bce_elem(float x, int t) {
    float tf = (t != 0) ? 1.0f : 0.0f;
    float ax = fabsf(x);
    float e = __expf(-ax);
    return fmaxf(x, 0.0f) - x * tf + __logf(1.0f + e);
}

__global__ __launch_bounds__(BLOCK) void bce_partial_kernel(
    const float* __restrict__ x, const int* __restrict__ t,
    float* __restrict__ partial, int n4) {
    const float4* __restrict__ x4 = (const float4*)x;
    const int4* __restrict__ t4 = (const int4*)t;

    float acc = 0.0f;
    const int stride = gridDim.x * blockDim.x;
    for (int i = blockIdx.x * blockDim.x + threadIdx.x; i < n4; i += stride) {
        float4 xv = x4[i];
        int4 tv = t4[i];
        acc += bce_elem(xv.x, tv.x);
        acc += bce_elem(xv.y, tv.y);
        acc += bce_elem(xv.z, tv.z);
        acc += bce_elem(xv.w, tv.w);
    }

    // wave-64 reduction
    #pragma unroll
    for (int off = 32; off > 0; off >>= 1)
        acc += __shfl_down(acc, off, 64);

    __shared__ float wsum[NWAVES];
    const int lane = threadIdx.x & 63;
    const int wave = threadIdx.x >> 6;
    if (lane == 0) wsum[wave] = acc;
    __syncthreads();
    if (threadIdx.x == 0) {
        float s = 0.0f;
        #pragma unroll
        for (int w = 0; w < NWAVES; w++) s += wsum[w];
        partial[blockIdx.x] = s;
    }
}

__global__ __launch_bounds__(BLOCK) void bce_final_kernel(
    const float* __restrict__ partial, float* __restrict__ out,
    int n_partial, double inv_n) {
    double acc = 0.0;
    for (int i = threadIdx.x; i < n_partial; i += BLOCK)
        acc += (double)partial[i];

    #pragma unroll
    for (int off = 32; off > 0; off >>= 1)
        acc += __shfl_down(acc, off, 64);

    __shared__ double wsum[NWAVES];
    const int lane = threadIdx.x & 63;
    const int wave = threadIdx.x >> 6;
    if (lane == 0) wsum[wave] = acc;
    __syncthreads();
    if (threadIdx.x == 0) {
        double s = 0.0;
        #pragma unroll
        for (int w = 0; w < NWAVES; w++) s += wsum[w];
        out[0] = (float)(s * inv_n);
    }
}

extern "C" void kernel_launch(void* const* d_in, const int* in_sizes, int n_in,
                              void* d_out, int out_size, void* d_ws, size_t ws_size,
                              hipStream_t stream) {
    const float* x = (const float*)d_in[0];
    const int* t = (const int*)d_in[1];
    float* out = (float*)d_out;
    float* partial = (float*)d_ws;  // GRID floats of scratch

    const long long n = (long long)in_sizes[0];  // 8192*8192 = 67108864, divisible by 4
    const int n4 = (int)(n / 4);

    bce_partial_kernel<<<GRID, BLOCK, 0, stream>>>(x, t, partial, n4);
    bce_final_kernel<<<1, BLOCK, 0, stream>>>(partial, out, GRID, 1.0 / (double)n);
}

// Round 3
// 473.724 us; speedup vs baseline: 1.0604x; 1.0604x over previous
//
#include <hip/hip_runtime.h>

#define BLOCK 256
#define GRID 2048
#define NWAVES (BLOCK / 64)

typedef float f32x4 __attribute__((ext_vector_type(4)));
typedef int i32x4 __attribute__((ext_vector_type(4)));

// per-element BCE-with-logits: max(x,0) - x*t + log(1 + exp(-|x|))
// == softplus(x) for t=0, softplus(-x) for t=1  (matches -where(t==0, -sp(x), -sp(-x)))
__device__ __forceinline__ float bce_elem(float x, int t) {
    float tf = (t != 0) ? 1.0f : 0.0f;
    float ax = fabsf(x);
    float e = __expf(-ax);
    return fmaxf(x, 0.0f) - x * tf + __logf(1.0f + e);
}

__device__ __forceinline__ float bce_quad(f32x4 xv, i32x4 tv) {
    return bce_elem(xv.x, tv.x) + bce_elem(xv.y, tv.y) +
           bce_elem(xv.z, tv.z) + bce_elem(xv.w, tv.w);
}

__global__ __launch_bounds__(BLOCK) void bce_partial_kernel(
    const float* __restrict__ x, const int* __restrict__ t,
    float* __restrict__ partial, int n4) {
    const f32x4* __restrict__ x4 = (const f32x4*)x;
    const i32x4* __restrict__ t4 = (const i32x4*)t;

    float acc = 0.0f;
    const int stride = gridDim.x * blockDim.x;
    int i = blockIdx.x * blockDim.x + threadIdx.x;

    // unroll-2: 4 outstanding nontemporal 16B loads per iteration
    for (; i + stride < n4; i += 2 * stride) {
        f32x4 xa = __builtin_nontemporal_load(&x4[i]);
        f32x4 xb = __builtin_nontemporal_load(&x4[i + stride]);
        i32x4 ta = __builtin_nontemporal_load(&t4[i]);
        i32x4 tb = __builtin_nontemporal_load(&t4[i + stride]);
        acc += bce_quad(xa, ta);
        acc += bce_quad(xb, tb);
    }
    if (i < n4) {
        f32x4 xa = __builtin_nontemporal_load(&x4[i]);
        i32x4 ta = __builtin_nontemporal_load(&t4[i]);
        acc += bce_quad(xa, ta);
    }

    // wave-64 reduction
    #pragma unroll
    for (int off = 32; off > 0; off >>= 1)
        acc += __shfl_down(acc, off, 64);

    __shared__ float wsum[NWAVES];
    const int lane = threadIdx.x & 63;
    const int wave = threadIdx.x >> 6;
    if (lane == 0) wsum[wave] = acc;
    __syncthreads();
    if (threadIdx.x == 0) {
        float s = 0.0f;
        #pragma unroll
        for (int w = 0; w < NWAVES; w++) s += wsum[w];
        partial[blockIdx.x] = s;
    }
}

__global__ __launch_bounds__(BLOCK) void bce_final_kernel(
    const float* __restrict__ partial, float* __restrict__ out,
    int n_partial, double inv_n) {
    double acc = 0.0;
    for (int i = threadIdx.x; i < n_partial; i += BLOCK)
        acc += (double)partial[i];

    #pragma unroll
    for (int off = 32; off > 0; off >>= 1)
        acc += __shfl_down(acc, off, 64);

    __shared__ double wsum[NWAVES];
    const int lane = threadIdx.x & 63;
    const int wave = threadIdx.x >> 6;
    if (lane == 0) wsum[wave] = acc;
    __syncthreads();
    if (threadIdx.x == 0) {
        double s = 0.0;
        #pragma unroll
        for (int w = 0; w < NWAVES; w++) s += wsum[w];
        out[0] = (float)(s * inv_n);
    }
}

extern "C" void kernel_launch(void* const* d_in, const int* in_sizes, int n_in,
                              void* d_out, int out_size, void* d_ws, size_t ws_size,
                              hipStream_t stream) {
    const float* x = (const float*)d_in[0];
    const int* t = (const int*)d_in[1];
    float* out = (float*)d_out;
    float* partial = (float*)d_ws;  // GRID floats of scratch

    const long long n = (long long)in_sizes[0];  // 8192*8192 = 67108864, divisible by 4
    const int n4 = (int)(n / 4);

    bce_partial_kernel<<<GRID, BLOCK, 0, stream>>>(x, t, partial, n4);
    bce_final_kernel<<<1, BLOCK, 0, stream>>>(partial, out, GRID, 1.0 / (double)n);
}